// Round 2
// baseline (315.946 us; speedup 1.0000x reference)
//
#include <hip/hip_runtime.h>

#define NCV 100000
#define NTV 300000
#define NPV 50000
#define OUTC 10
#define EMV 300000
#define EIV 600000
#define YST 16   // y_c / y_p row stride (floats) -> 64B-aligned rows

// ---------------- fused weight folding (block 0, T/Q in LDS) + heads init (blocks>0) ----
// T1 = Wn10@Wout, T2 = Wn12@Wout, T3 = 0.5*(Wr10+Wr12)@Wout          (each 128x10, LDS)
// Q1=Wn01@T1 Q2=Wr01@T1 Q3=Wn03@T2 Q4=Wr03@T2 Q5=Wn00@T3 Q6=Wn02@T3 Q7=(Wr00+Wr02)@T3
// B: final 45x10 table (rows 0..16 B_c | 17..33 B_p | 34..41 B_t | 42 u_c | 43 u_p | 44 k)
__global__ __launch_bounds__(256) void fold_init(
    const float* __restrict__ Wcol, const float* __restrict__ bcol,
    const float* __restrict__ Wn, const float* __restrict__ Wr,
    const float* __restrict__ b_lin, const float* __restrict__ Wout,
    const float* __restrict__ bout,
    int* __restrict__ heads, int nheads, float* __restrict__ B) {
  __shared__ float sWout[1280];   // 128x10
  __shared__ float sT[3840];      // 3 x 128 x 10
  __shared__ float sQ[8960];      // 7 x 128 x 10
  int tid = threadIdx.x;

  if (blockIdx.x != 0) {   // heads init to -1
    int i = (blockIdx.x - 1) * 256 + tid;
    int stride = (gridDim.x - 1) * 256;
    for (; i < nheads; i += stride) heads[i] = -1;
    return;
  }

  for (int i = tid; i < 1280; i += 256) sWout[i] = Wout[i];
  __syncthreads();

  const float* Wn00 = Wn;             const float* Wn01 = Wn + 1 * 16384;
  const float* Wn02 = Wn + 2 * 16384; const float* Wn03 = Wn + 3 * 16384;
  const float* Wn10 = Wn + 4 * 16384; const float* Wn12 = Wn + 6 * 16384;
  const float* Wr00 = Wr;             const float* Wr01 = Wr + 1 * 16384;
  const float* Wr02 = Wr + 2 * 16384; const float* Wr03 = Wr + 3 * 16384;
  const float* Wr10 = Wr + 4 * 16384; const float* Wr12 = Wr + 6 * 16384;

  // ---- T phase: 3 mats x 128 rows; one row-task per thread-iteration ----
  for (int task = tid; task < 3 * 128; task += 256) {
    int mat = task >> 7, n = task & 127;
    float acc[10];
    #pragma unroll
    for (int o = 0; o < 10; ++o) acc[o] = 0.f;
    for (int m = 0; m < 128; m += 4) {
      float4 w4;
      if (mat == 0) w4 = *(const float4*)(Wn10 + n * 128 + m);
      else if (mat == 1) w4 = *(const float4*)(Wn12 + n * 128 + m);
      else {
        float4 a = *(const float4*)(Wr10 + n * 128 + m);
        float4 b = *(const float4*)(Wr12 + n * 128 + m);
        w4 = make_float4(0.5f * (a.x + b.x), 0.5f * (a.y + b.y),
                         0.5f * (a.z + b.z), 0.5f * (a.w + b.w));
      }
      const float* wo = &sWout[m * 10];
      #pragma unroll
      for (int o = 0; o < 10; ++o)
        acc[o] += w4.x * wo[o] + w4.y * wo[10 + o] + w4.z * wo[20 + o] + w4.w * wo[30 + o];
    }
    #pragma unroll
    for (int o = 0; o < 10; ++o) sT[task * 10 + o] = acc[o];
  }
  __syncthreads();

  // ---- Q phase: 7 products x 128 rows ----
  for (int task = tid; task < 7 * 128; task += 256) {
    int q = task / 128, k = task & 127;
    const float* Tsel = &sT[(q < 2 ? 0 : (q < 4 ? 1 : 2)) * 1280];
    float acc[10];
    #pragma unroll
    for (int o = 0; o < 10; ++o) acc[o] = 0.f;
    for (int n = 0; n < 128; n += 4) {
      float4 w4;
      switch (q) {
        case 0: w4 = *(const float4*)(Wn01 + k * 128 + n); break;
        case 1: w4 = *(const float4*)(Wr01 + k * 128 + n); break;
        case 2: w4 = *(const float4*)(Wn03 + k * 128 + n); break;
        case 3: w4 = *(const float4*)(Wr03 + k * 128 + n); break;
        case 4: w4 = *(const float4*)(Wn00 + k * 128 + n); break;
        case 5: w4 = *(const float4*)(Wn02 + k * 128 + n); break;
        default: {
          float4 a = *(const float4*)(Wr00 + k * 128 + n);
          float4 b = *(const float4*)(Wr02 + k * 128 + n);
          w4 = make_float4(a.x + b.x, a.y + b.y, a.z + b.z, a.w + b.w);
        } break;
      }
      const float* tr = &Tsel[n * 10];
      #pragma unroll
      for (int o = 0; o < 10; ++o)
        acc[o] += w4.x * tr[o] + w4.y * tr[10 + o] + w4.z * tr[20 + o] + w4.w * tr[30 + o];
    }
    #pragma unroll
    for (int o = 0; o < 10; ++o) sQ[task * 10 + o] = acc[o];
  }
  __syncthreads();

  // ---- B phase: 450 outputs ----
  const float* WcC = Wcol, *WcT = Wcol + 128, *WcP = Wcol + 256;
  const float* bC = bcol, *bT = bcol + 128, *bP = bcol + 256;
  const float* Q1 = sQ, *Q2 = sQ + 1280, *Q3 = sQ + 2560, *Q4 = sQ + 3840;
  const float* Q5 = sQ + 5120, *Q6 = sQ + 6400, *Q7 = sQ + 7680;
  const float* T1 = sT, *T2 = sT + 1280, *T3 = sT + 2560;
  const float* b00 = b_lin, *b01 = b_lin + 128, *b02 = b_lin + 256, *b03 = b_lin + 384;
  const float* b10 = b_lin + 512, *b12 = b_lin + 768;
  for (int task = tid; task < 450; task += 256) {
    int r = task / 10, o = task % 10;
    float s = 0.f;
    if (r < 8) {
      for (int j = 0; j < 16; ++j) s += WcT[r * 16 + j] * Q1[(r * 16 + j) * 10 + o];
    } else if (r < 16) {
      int jr = r - 8;
      for (int j = 0; j < 16; ++j)
        s += WcC[jr * 16 + j] * (Q2[(jr * 16 + j) * 10 + o] + Q5[(jr * 16 + j) * 10 + o]);
    } else if (r == 16) {
      for (int k2 = 0; k2 < 128; ++k2) s += bT[k2] * Q1[k2 * 10 + o];
    } else if (r < 25) {
      int jr = r - 17;
      for (int j = 0; j < 16; ++j) s += WcT[jr * 16 + j] * Q3[(jr * 16 + j) * 10 + o];
    } else if (r < 33) {
      int jr = r - 25;
      for (int j = 0; j < 16; ++j)
        s += WcP[jr * 16 + j] * (Q4[(jr * 16 + j) * 10 + o] + Q6[(jr * 16 + j) * 10 + o]);
    } else if (r == 33) {
      for (int k2 = 0; k2 < 128; ++k2) s += bT[k2] * Q3[k2 * 10 + o];
    } else if (r < 42) {
      int jr = r - 34;
      for (int j = 0; j < 16; ++j) s += WcT[jr * 16 + j] * Q7[(jr * 16 + j) * 10 + o];
    } else if (r == 42) {
      for (int k2 = 0; k2 < 128; ++k2)
        s += bC[k2] * (Q2[k2 * 10 + o] + Q5[k2 * 10 + o]) + b01[k2] * T1[k2 * 10 + o];
    } else if (r == 43) {
      for (int k2 = 0; k2 < 128; ++k2)
        s += bP[k2] * (Q4[k2 * 10 + o] + Q6[k2 * 10 + o]) + b03[k2] * T2[k2 * 10 + o];
    } else {
      for (int n = 0; n < 128; ++n)
        s += (b10[n] + b12[n]) * sWout[n * 10 + o] + bT[n] * Q7[n * 10 + o] +
             (b00[n] + b02[n]) * T3[n * 10 + o];
    }
    float v = s * 0.5f;
    if (r == 44) v += bout[o];
    B[task] = v;
  }
}

// ---------------- build per-destination linked lists, 4 edges per thread (int4) ----------
// head_c : makes-edges by customer | head_tm : makes-edges by transaction
// head_p : in-edges by product     | head_ti : in-edges by transaction
__global__ __launch_bounds__(256) void build_lists(
    const int* __restrict__ ems, const int* __restrict__ emd,
    const int* __restrict__ eis, const int* __restrict__ eid,
    int* __restrict__ head_c, int* __restrict__ head_tm,
    int* __restrict__ head_p, int* __restrict__ head_ti,
    int* __restrict__ nxt_mc, int* __restrict__ nxt_mt,
    int* __restrict__ nxt_ip, int* __restrict__ nxt_it) {
  int g = blockIdx.x * 256 + threadIdx.x;
  int e0 = g * 4;
  if (e0 < EMV) {
    int4 s = ((const int4*)ems)[g];
    int4 d = ((const int4*)emd)[g];
    int4 n0, n1;
    n0.x = atomicExch(&head_c[s.x], e0);
    n0.y = atomicExch(&head_c[s.y], e0 + 1);
    n0.z = atomicExch(&head_c[s.z], e0 + 2);
    n0.w = atomicExch(&head_c[s.w], e0 + 3);
    n1.x = atomicExch(&head_tm[d.x], e0);
    n1.y = atomicExch(&head_tm[d.y], e0 + 1);
    n1.z = atomicExch(&head_tm[d.z], e0 + 2);
    n1.w = atomicExch(&head_tm[d.w], e0 + 3);
    ((int4*)nxt_mc)[g] = n0;
    ((int4*)nxt_mt)[g] = n1;
  }
  if (e0 < EIV) {
    int4 s = ((const int4*)eis)[g];
    int4 d = ((const int4*)eid)[g];
    int4 n0, n1;
    n0.x = atomicExch(&head_p[s.x], e0);
    n0.y = atomicExch(&head_p[s.y], e0 + 1);
    n0.z = atomicExch(&head_p[s.z], e0 + 2);
    n0.w = atomicExch(&head_p[s.w], e0 + 3);
    n1.x = atomicExch(&head_ti[d.x], e0);
    n1.y = atomicExch(&head_ti[d.y], e0 + 1);
    n1.z = atomicExch(&head_ti[d.z], e0 + 2);
    n1.w = atomicExch(&head_ti[d.w], e0 + 3);
    ((int4*)nxt_ip)[g] = n0;
    ((int4*)nxt_it)[g] = n1;
  }
}

// ---------------- gather + finalize y for customers and products -------------------
// Per node: walk its edge list, accumulate x_t rows (mean), then project through B.
// z = [g·x̄_t, x_own, g] -> y = z @ B_side (10 floats)
__global__ __launch_bounds__(256) void gather_y(
    const float* __restrict__ xt,
    const int* __restrict__ emd, const int* __restrict__ eid,
    const int* __restrict__ head_c, const int* __restrict__ head_p,
    const int* __restrict__ nxt_mc, const int* __restrict__ nxt_ip,
    const float* __restrict__ xc, const float* __restrict__ xp,
    const float* __restrict__ B,
    float* __restrict__ y_c, float* __restrict__ y_p) {
  __shared__ float sB[340];   // rows 0..33 of B
  int tid = threadIdx.x;
  for (int i = tid; i < 340; i += 256) sB[i] = B[i];
  __syncthreads();
  int i = blockIdx.x * 256 + tid;
  if (i >= NCV + NPV) return;
  bool isC = i < NCV;
  int idx = isC ? i : i - NCV;
  const int* dstA = isC ? emd : eid;
  const int* nxt = isC ? nxt_mc : nxt_ip;
  int e = isC ? head_c[idx] : head_p[idx];

  float acc[8] = {0.f, 0.f, 0.f, 0.f, 0.f, 0.f, 0.f, 0.f};
  float cnt = 0.f;
  while (e >= 0) {
    const float4* xr = (const float4*)(xt + (size_t)dstA[e] * 8);
    float4 u = xr[0], v = xr[1];
    acc[0] += u.x; acc[1] += u.y; acc[2] += u.z; acc[3] += u.w;
    acc[4] += v.x; acc[5] += v.y; acc[6] += v.z; acc[7] += v.w;
    cnt += 1.f;
    e = nxt[e];
  }

  const float* xo = (isC ? xc : xp) + (size_t)idx * 8;
  const float* Bs = sB + (isC ? 0 : 170);
  float g = cnt > 0.f ? 1.f : 0.f;
  float inv = g / fmaxf(cnt, 1.f);
  float lg[OUTC];
  #pragma unroll
  for (int o = 0; o < OUTC; ++o) lg[o] = g * Bs[16 * 10 + o];
  #pragma unroll
  for (int r = 0; r < 8; ++r) {
    float zb = acc[r] * inv;
    float zo = xo[r];
    #pragma unroll
    for (int o = 0; o < OUTC; ++o)
      lg[o] += zb * Bs[r * 10 + o] + zo * Bs[(8 + r) * 10 + o];
  }
  float* y = (isC ? y_c : y_p) + (size_t)idx * YST;
  #pragma unroll
  for (int o = 0; o < OUTC; ++o) y[o] = lg[o];
}

// ---------------- gather y into each transaction + final combine + softmax ----------
__global__ __launch_bounds__(256) void gather_t(
    const float* __restrict__ y_c, const float* __restrict__ y_p,
    const float* __restrict__ xt,
    const int* __restrict__ ems, const int* __restrict__ eis,
    const int* __restrict__ head_tm, const int* __restrict__ head_ti,
    const int* __restrict__ nxt_mt, const int* __restrict__ nxt_it,
    const float* __restrict__ B, float* __restrict__ out) {
  __shared__ float sB[110];   // rows 34..44 of B
  int tid = threadIdx.x;
  for (int i = tid; i < 110; i += 256) sB[i] = B[340 + i];
  __syncthreads();
  int t = blockIdx.x * 256 + tid;
  if (t >= NTV) return;

  float sc[OUTC] = {0.f, 0.f, 0.f, 0.f, 0.f, 0.f, 0.f, 0.f, 0.f, 0.f};
  float sp[OUTC] = {0.f, 0.f, 0.f, 0.f, 0.f, 0.f, 0.f, 0.f, 0.f, 0.f};
  float dc = 0.f, dp = 0.f;
  for (int e = head_tm[t]; e >= 0; e = nxt_mt[e]) {
    const float* yr = y_c + (size_t)ems[e] * YST;
    float4 u = *(const float4*)yr;
    float4 v = *(const float4*)(yr + 4);
    float2 w = *(const float2*)(yr + 8);
    sc[0] += u.x; sc[1] += u.y; sc[2] += u.z; sc[3] += u.w;
    sc[4] += v.x; sc[5] += v.y; sc[6] += v.z; sc[7] += v.w;
    sc[8] += w.x; sc[9] += w.y;
    dc += 1.f;
  }
  for (int e = head_ti[t]; e >= 0; e = nxt_it[e]) {
    const float* yr = y_p + (size_t)eis[e] * YST;
    float4 u = *(const float4*)yr;
    float4 v = *(const float4*)(yr + 4);
    float2 w = *(const float2*)(yr + 8);
    sp[0] += u.x; sp[1] += u.y; sp[2] += u.z; sp[3] += u.w;
    sp[4] += v.x; sp[5] += v.y; sp[6] += v.z; sp[7] += v.w;
    sp[8] += w.x; sp[9] += w.y;
    dp += 1.f;
  }

  float Gc = dc > 0.f ? 1.f : 0.f, Gp = dp > 0.f ? 1.f : 0.f;
  float ivc = 1.f / fmaxf(dc, 1.f), ivp = 1.f / fmaxf(dp, 1.f);

  const float4* xp4 = (const float4*)(xt + (size_t)t * 8);
  float4 xa = xp4[0], xb = xp4[1];
  float xv[8] = {xa.x, xa.y, xa.z, xa.w, xb.x, xb.y, xb.z, xb.w};

  float lg[OUTC];
  #pragma unroll
  for (int o = 0; o < OUTC; ++o)
    lg[o] = sc[o] * ivc + sp[o] * ivp +
            Gc * sB[80 + o] + Gp * sB[90 + o] + sB[100 + o];
  #pragma unroll
  for (int r = 0; r < 8; ++r) {
    float xr = xv[r];
    #pragma unroll
    for (int o = 0; o < OUTC; ++o) lg[o] += xr * sB[r * 10 + o];
  }

  float m = lg[0];
  #pragma unroll
  for (int o = 1; o < OUTC; ++o) m = fmaxf(m, lg[o]);
  float s = 0.f;
  #pragma unroll
  for (int o = 0; o < OUTC; ++o) { lg[o] = __expf(lg[o] - m); s += lg[o]; }
  float invs = 1.0f / s;
  float* op = &out[(size_t)t * OUTC];
  #pragma unroll
  for (int o = 0; o < 5; ++o) {
    float2 p2; p2.x = lg[2 * o] * invs; p2.y = lg[2 * o + 1] * invs;
    *(float2*)&op[2 * o] = p2;
  }
}

extern "C" void kernel_launch(void* const* d_in, const int* in_sizes, int n_in,
                              void* d_out, int out_size, void* d_ws, size_t ws_size,
                              hipStream_t stream) {
  const float* x_c   = (const float*)d_in[0];
  const float* x_t   = (const float*)d_in[1];
  const float* x_p   = (const float*)d_in[2];
  const float* W_col = (const float*)d_in[3];
  const float* b_col = (const float*)d_in[4];
  const float* Wn    = (const float*)d_in[5];
  const float* Wr    = (const float*)d_in[6];
  const float* b_lin = (const float*)d_in[7];
  const float* W_out = (const float*)d_in[8];
  const float* b_out = (const float*)d_in[9];
  const int* e_m_src = (const int*)d_in[10];
  const int* e_m_dst = (const int*)d_in[11];
  const int* e_i_src = (const int*)d_in[12];
  const int* e_i_dst = (const int*)d_in[13];
  float* out = (float*)d_out;

  // ---- workspace carve-out (~20 MB; ws_size = 256 MiB) ----
  size_t cursor = 0;
  char* base = (char*)d_ws;
  auto alloc = [&](size_t bytes) {
    void* p = base + cursor;
    cursor += (bytes + 255) & ~(size_t)255;
    return p;
  };
  float* y_c  = (float*)alloc((size_t)NCV * YST * 4);              // 6.4 MB
  float* y_p  = (float*)alloc((size_t)NPV * YST * 4);              // 3.2 MB
  int nheads = NCV + NPV + 2 * NTV;
  int* heads  = (int*)alloc((size_t)nheads * 4);                   // 3.0 MB
  int* head_c  = heads;
  int* head_p  = heads + NCV;
  int* head_tm = heads + NCV + NPV;
  int* head_ti = heads + NCV + NPV + NTV;
  int* nxt_mc = (int*)alloc((size_t)EMV * 4);                      // 1.2 MB
  int* nxt_mt = (int*)alloc((size_t)EMV * 4);                      // 1.2 MB
  int* nxt_ip = (int*)alloc((size_t)EIV * 4);                      // 2.4 MB
  int* nxt_it = (int*)alloc((size_t)EIV * 4);                      // 2.4 MB
  float* B    = (float*)alloc(450 * 4);

  // ---- fused folding + heads init (replaces memset + 3 prep kernels) ----
  fold_init<<<129, 256, 0, stream>>>(
      W_col, b_col, Wn, Wr, b_lin, W_out, b_out, heads, nheads, B);

  // ---- build per-destination edge lists (4 edges/thread, int4 batched) ----
  build_lists<<<(EIV / 4 + 255) / 256, 256, 0, stream>>>(
      e_m_src, e_m_dst, e_i_src, e_i_dst,
      head_c, head_tm, head_p, head_ti,
      nxt_mc, nxt_mt, nxt_ip, nxt_it);

  // ---- gather x_t into customers/products + project through B ----
  gather_y<<<(NCV + NPV + 255) / 256, 256, 0, stream>>>(
      x_t, e_m_dst, e_i_dst, head_c, head_p, nxt_mc, nxt_ip,
      x_c, x_p, B, y_c, y_p);

  // ---- gather y into transactions + combine + softmax ----
  gather_t<<<(NTV + 255) / 256, 256, 0, stream>>>(
      y_c, y_p, x_t, e_m_src, e_i_src, head_tm, head_ti,
      nxt_mt, nxt_it, B, out);
}

// Round 3
// 276.808 us; speedup vs baseline: 1.1414x; 1.1414x over previous
//
#include <hip/hip_runtime.h>

#define NCV 100000
#define NTV 300000
#define NPV 50000
#define OUTC 10
#define EMV 300000
#define EIV 600000
#define YST 16   // y_c / y_p row stride (floats) -> 64B-aligned rows

// ---------------- K0: per-column weight folding (blocks 0..9) + heads init (blocks 10+) ----
// Column o of: T1=Wn10@Wout, T2=Wn12@Wout, T3=0.5*(Wr10+Wr12)@Wout (128 each, LDS)
//             Q1=Wn01@T1 Q2=Wr01@T1 Q3=Wn03@T2 Q4=Wr03@T2 Q5=Wn00@T3 Q6=Wn02@T3 Q7=(Wr00+Wr02)@T3
//             B[:,o]: 45 entries (0..16 B_c | 17..33 B_p | 34..41 B_t | 42 u_c | 43 u_p | 44 k)
__global__ __launch_bounds__(256) void fold_heads(
    const float* __restrict__ Wcol, const float* __restrict__ bcol,
    const float* __restrict__ Wn, const float* __restrict__ Wr,
    const float* __restrict__ b_lin, const float* __restrict__ Wout,
    const float* __restrict__ bout,
    int* __restrict__ heads, int nheads, float* __restrict__ B) {
  int tid = threadIdx.x;
  if (blockIdx.x >= 10) {   // heads init to -1
    int i = (blockIdx.x - 10) * 256 + tid;
    int stride = (gridDim.x - 10) * 256;
    for (; i < nheads; i += stride) heads[i] = -1;
    return;
  }
  __shared__ float sWo[128];
  __shared__ float sT[3][128];
  __shared__ float sQ[7][128];
  const int o = blockIdx.x;
  if (tid < 128) sWo[tid] = Wout[tid * 10 + o];
  __syncthreads();

  const float* Wn00 = Wn;               const float* Wn01 = Wn + 16384;
  const float* Wn02 = Wn + 2 * 16384;   const float* Wn03 = Wn + 3 * 16384;
  const float* Wn10 = Wn + 4 * 16384;   const float* Wn12 = Wn + 6 * 16384;
  const float* Wr00 = Wr;               const float* Wr01 = Wr + 16384;
  const float* Wr02 = Wr + 2 * 16384;   const float* Wr03 = Wr + 3 * 16384;
  const float* Wr10 = Wr + 4 * 16384;   const float* Wr12 = Wr + 6 * 16384;

  // ---- T phase: 3 mats x 128 rows, one dot(128) per task ----
  for (int task = tid; task < 384; task += 256) {
    int mat = task >> 7, n = task & 127;
    float acc = 0.f;
    if (mat == 0) {
      const float4* w = (const float4*)(Wn10 + n * 128);
      for (int m = 0; m < 32; ++m) {
        float4 w4 = w[m];
        acc += w4.x * sWo[4 * m] + w4.y * sWo[4 * m + 1] +
               w4.z * sWo[4 * m + 2] + w4.w * sWo[4 * m + 3];
      }
    } else if (mat == 1) {
      const float4* w = (const float4*)(Wn12 + n * 128);
      for (int m = 0; m < 32; ++m) {
        float4 w4 = w[m];
        acc += w4.x * sWo[4 * m] + w4.y * sWo[4 * m + 1] +
               w4.z * sWo[4 * m + 2] + w4.w * sWo[4 * m + 3];
      }
    } else {
      const float4* wa = (const float4*)(Wr10 + n * 128);
      const float4* wb = (const float4*)(Wr12 + n * 128);
      for (int m = 0; m < 32; ++m) {
        float4 a = wa[m], b = wb[m];
        acc += 0.5f * ((a.x + b.x) * sWo[4 * m] + (a.y + b.y) * sWo[4 * m + 1] +
                       (a.z + b.z) * sWo[4 * m + 2] + (a.w + b.w) * sWo[4 * m + 3]);
      }
    }
    sT[mat][n] = acc;
  }
  __syncthreads();

  // ---- Q phase: 7 mats x 128 rows ----
  for (int task = tid; task < 896; task += 256) {
    int q = task / 128, k = task & 127;
    const float* Tc = sT[q < 2 ? 0 : (q < 4 ? 1 : 2)];
    const float4* w; const float4* w2 = nullptr;
    switch (q) {
      case 0: w = (const float4*)(Wn01 + k * 128); break;
      case 1: w = (const float4*)(Wr01 + k * 128); break;
      case 2: w = (const float4*)(Wn03 + k * 128); break;
      case 3: w = (const float4*)(Wr03 + k * 128); break;
      case 4: w = (const float4*)(Wn00 + k * 128); break;
      case 5: w = (const float4*)(Wn02 + k * 128); break;
      default: w = (const float4*)(Wr00 + k * 128); w2 = (const float4*)(Wr02 + k * 128); break;
    }
    float acc = 0.f;
    for (int n = 0; n < 32; ++n) {
      float4 w4 = w[n];
      if (w2) { float4 b = w2[n]; w4.x += b.x; w4.y += b.y; w4.z += b.z; w4.w += b.w; }
      acc += w4.x * Tc[4 * n] + w4.y * Tc[4 * n + 1] +
             w4.z * Tc[4 * n + 2] + w4.w * Tc[4 * n + 3];
    }
    sQ[q][k] = acc;
  }
  __syncthreads();

  // ---- B phase: 45 rows of column o ----
  if (tid < 45) {
    int r = tid;
    const float* WcC = Wcol, *WcT = Wcol + 128, *WcP = Wcol + 256;
    const float* bC = bcol, *bT = bcol + 128, *bP = bcol + 256;
    const float* b00 = b_lin, *b01 = b_lin + 128, *b02 = b_lin + 256, *b03 = b_lin + 384;
    const float* b10 = b_lin + 512, *b12 = b_lin + 768;
    float s = 0.f;
    if (r < 8) {
      for (int j = 0; j < 16; ++j) s += WcT[r * 16 + j] * sQ[0][r * 16 + j];
    } else if (r < 16) {
      int jr = r - 8;
      for (int j = 0; j < 16; ++j)
        s += WcC[jr * 16 + j] * (sQ[1][jr * 16 + j] + sQ[4][jr * 16 + j]);
    } else if (r == 16) {
      for (int k = 0; k < 128; ++k) s += bT[k] * sQ[0][k];
    } else if (r < 25) {
      int jr = r - 17;
      for (int j = 0; j < 16; ++j) s += WcT[jr * 16 + j] * sQ[2][jr * 16 + j];
    } else if (r < 33) {
      int jr = r - 25;
      for (int j = 0; j < 16; ++j)
        s += WcP[jr * 16 + j] * (sQ[3][jr * 16 + j] + sQ[5][jr * 16 + j]);
    } else if (r == 33) {
      for (int k = 0; k < 128; ++k) s += bT[k] * sQ[2][k];
    } else if (r < 42) {
      int jr = r - 34;
      for (int j = 0; j < 16; ++j) s += WcT[jr * 16 + j] * sQ[6][jr * 16 + j];
    } else if (r == 42) {
      for (int k = 0; k < 128; ++k)
        s += bC[k] * (sQ[1][k] + sQ[4][k]) + b01[k] * sT[0][k];
    } else if (r == 43) {
      for (int k = 0; k < 128; ++k)
        s += bP[k] * (sQ[3][k] + sQ[5][k]) + b03[k] * sT[1][k];
    } else {
      for (int n = 0; n < 128; ++n)
        s += (b10[n] + b12[n]) * sWo[n] + bT[n] * sQ[6][n] + (b00[n] + b02[n]) * sT[2][n];
    }
    float v = s * 0.5f;
    if (r == 44) v += bout[o];
    B[r * 10 + o] = v;
  }
}

// ---------------- K1: build customer/product-side lists, node payload packed in int2 ----
// nxt2[e] = {next_edge, t_index}
__global__ __launch_bounds__(256) void build_cp(
    const int* __restrict__ ems, const int* __restrict__ emd,
    const int* __restrict__ eis, const int* __restrict__ eid,
    int* __restrict__ head_c, int* __restrict__ head_p,
    int2* __restrict__ nxt2_mc, int2* __restrict__ nxt2_ip) {
  int g = blockIdx.x * 256 + threadIdx.x;
  if (g >= EIV / 4) return;
  int e0 = g * 4;
  if (g < EMV / 4) {
    int4 s = ((const int4*)ems)[g];
    int4 d = ((const int4*)emd)[g];
    int4 o0, o1;
    o0.x = atomicExch(&head_c[s.x], e0);     o0.y = d.x;
    o0.z = atomicExch(&head_c[s.y], e0 + 1); o0.w = d.y;
    o1.x = atomicExch(&head_c[s.z], e0 + 2); o1.y = d.z;
    o1.z = atomicExch(&head_c[s.w], e0 + 3); o1.w = d.w;
    ((int4*)nxt2_mc)[2 * g] = o0; ((int4*)nxt2_mc)[2 * g + 1] = o1;
  }
  {
    int4 s = ((const int4*)eis)[g];
    int4 d = ((const int4*)eid)[g];
    int4 o0, o1;
    o0.x = atomicExch(&head_p[s.x], e0);     o0.y = d.x;
    o0.z = atomicExch(&head_p[s.y], e0 + 1); o0.w = d.y;
    o1.x = atomicExch(&head_p[s.z], e0 + 2); o1.y = d.z;
    o1.z = atomicExch(&head_p[s.w], e0 + 3); o1.w = d.w;
    ((int4*)nxt2_ip)[2 * g] = o0; ((int4*)nxt2_ip)[2 * g + 1] = o1;
  }
}

// ---------------- K2: build transaction-side lists (overlapped) + gather/finalize y ----
// t-lists: nxt2[e] = {next_edge, src_index}. Then per c/p node: walk list, mean x_t,
// project z = [g*mean_xt, x_own, g] through B rows -> 10 floats.
__global__ __launch_bounds__(256) void gather_y_buildt(
    const float* __restrict__ xt,
    const int* __restrict__ ems, const int* __restrict__ emd,
    const int* __restrict__ eis, const int* __restrict__ eid,
    const int* __restrict__ head_c, const int* __restrict__ head_p,
    const int2* __restrict__ nxt2_mc, const int2* __restrict__ nxt2_ip,
    int* __restrict__ head_tm, int* __restrict__ head_ti,
    int2* __restrict__ nxt2_mt, int2* __restrict__ nxt2_it,
    const float* __restrict__ xc, const float* __restrict__ xp,
    const float* __restrict__ B,
    float* __restrict__ y_c, float* __restrict__ y_p) {
  __shared__ float sB[340];   // rows 0..33 of B
  int tid = threadIdx.x;
  for (int i = tid; i < 340; i += 256) sB[i] = B[i];
  int g = blockIdx.x * 256 + tid;

  // t-side list building: independent atomics, fabric latency hides under gather below
  if (g < EMV / 4) {
    int e0 = g * 4;
    int4 s = ((const int4*)ems)[g];
    int4 d = ((const int4*)emd)[g];
    int4 o0, o1;
    o0.x = atomicExch(&head_tm[d.x], e0);     o0.y = s.x;
    o0.z = atomicExch(&head_tm[d.y], e0 + 1); o0.w = s.y;
    o1.x = atomicExch(&head_tm[d.z], e0 + 2); o1.y = s.z;
    o1.z = atomicExch(&head_tm[d.w], e0 + 3); o1.w = s.w;
    ((int4*)nxt2_mt)[2 * g] = o0; ((int4*)nxt2_mt)[2 * g + 1] = o1;
  }
  if (g < EIV / 4) {
    int e0 = g * 4;
    int4 s = ((const int4*)eis)[g];
    int4 d = ((const int4*)eid)[g];
    int4 o0, o1;
    o0.x = atomicExch(&head_ti[d.x], e0);     o0.y = s.x;
    o0.z = atomicExch(&head_ti[d.y], e0 + 1); o0.w = s.y;
    o1.x = atomicExch(&head_ti[d.z], e0 + 2); o1.y = s.z;
    o1.z = atomicExch(&head_ti[d.w], e0 + 3); o1.w = s.w;
    ((int4*)nxt2_it)[2 * g] = o0; ((int4*)nxt2_it)[2 * g + 1] = o1;
  }
  __syncthreads();

  int i = g;
  if (i >= NCV + NPV) return;
  bool isC = i < NCV;
  int idx = isC ? i : i - NCV;
  const int2* nxt2 = isC ? nxt2_mc : nxt2_ip;
  int e = isC ? head_c[idx] : head_p[idx];

  float acc[8] = {0.f, 0.f, 0.f, 0.f, 0.f, 0.f, 0.f, 0.f};
  float cnt = 0.f;
  while (e >= 0) {
    int2 v = nxt2[e];
    const float4* xr = (const float4*)(xt + (size_t)v.y * 8);
    float4 u = xr[0], w = xr[1];
    acc[0] += u.x; acc[1] += u.y; acc[2] += u.z; acc[3] += u.w;
    acc[4] += w.x; acc[5] += w.y; acc[6] += w.z; acc[7] += w.w;
    cnt += 1.f;
    e = v.x;
  }

  const float* xo = (isC ? xc : xp) + (size_t)idx * 8;
  const float* Bs = sB + (isC ? 0 : 170);
  float gg = cnt > 0.f ? 1.f : 0.f;
  float inv = gg / fmaxf(cnt, 1.f);
  float lg[OUTC];
  #pragma unroll
  for (int o = 0; o < OUTC; ++o) lg[o] = gg * Bs[16 * 10 + o];
  #pragma unroll
  for (int r = 0; r < 8; ++r) {
    float zb = acc[r] * inv;
    float zo = xo[r];
    #pragma unroll
    for (int o = 0; o < OUTC; ++o)
      lg[o] += zb * Bs[r * 10 + o] + zo * Bs[(8 + r) * 10 + o];
  }
  float* y = (isC ? y_c : y_p) + (size_t)idx * YST;
  #pragma unroll
  for (int o = 0; o < OUTC; ++o) y[o] = lg[o];
}

// ---------------- K3: gather y into each transaction (dual interleaved chains) + softmax ----
__global__ __launch_bounds__(256) void gather_t(
    const float* __restrict__ y_c, const float* __restrict__ y_p,
    const float* __restrict__ xt,
    const int* __restrict__ head_tm, const int* __restrict__ head_ti,
    const int2* __restrict__ nxt2_mt, const int2* __restrict__ nxt2_it,
    const float* __restrict__ B, float* __restrict__ out) {
  __shared__ float sB[110];   // rows 34..44 of B
  int tid = threadIdx.x;
  for (int i = tid; i < 110; i += 256) sB[i] = B[340 + i];
  __syncthreads();
  int t = blockIdx.x * 256 + tid;
  if (t >= NTV) return;

  float sc[OUTC] = {0.f, 0.f, 0.f, 0.f, 0.f, 0.f, 0.f, 0.f, 0.f, 0.f};
  float sp[OUTC] = {0.f, 0.f, 0.f, 0.f, 0.f, 0.f, 0.f, 0.f, 0.f, 0.f};
  float dc = 0.f, dp = 0.f;
  int e1 = head_tm[t], e2 = head_ti[t];
  while (e1 >= 0 || e2 >= 0) {
    if (e1 >= 0) {
      int2 v = nxt2_mt[e1];
      const float* yr = y_c + (size_t)v.y * YST;
      float4 u = *(const float4*)yr;
      float4 w = *(const float4*)(yr + 4);
      float2 z = *(const float2*)(yr + 8);
      sc[0] += u.x; sc[1] += u.y; sc[2] += u.z; sc[3] += u.w;
      sc[4] += w.x; sc[5] += w.y; sc[6] += w.z; sc[7] += w.w;
      sc[8] += z.x; sc[9] += z.y;
      dc += 1.f;
      e1 = v.x;
    }
    if (e2 >= 0) {
      int2 v = nxt2_it[e2];
      const float* yr = y_p + (size_t)v.y * YST;
      float4 u = *(const float4*)yr;
      float4 w = *(const float4*)(yr + 4);
      float2 z = *(const float2*)(yr + 8);
      sp[0] += u.x; sp[1] += u.y; sp[2] += u.z; sp[3] += u.w;
      sp[4] += w.x; sp[5] += w.y; sp[6] += w.z; sp[7] += w.w;
      sp[8] += z.x; sp[9] += z.y;
      dp += 1.f;
      e2 = v.x;
    }
  }

  float Gc = dc > 0.f ? 1.f : 0.f, Gp = dp > 0.f ? 1.f : 0.f;
  float ivc = 1.f / fmaxf(dc, 1.f), ivp = 1.f / fmaxf(dp, 1.f);

  const float4* xp4 = (const float4*)(xt + (size_t)t * 8);
  float4 xa = xp4[0], xb = xp4[1];
  float xv[8] = {xa.x, xa.y, xa.z, xa.w, xb.x, xb.y, xb.z, xb.w};

  float lg[OUTC];
  #pragma unroll
  for (int o = 0; o < OUTC; ++o)
    lg[o] = sc[o] * ivc + sp[o] * ivp +
            Gc * sB[80 + o] + Gp * sB[90 + o] + sB[100 + o];
  #pragma unroll
  for (int r = 0; r < 8; ++r) {
    float xr = xv[r];
    #pragma unroll
    for (int o = 0; o < OUTC; ++o) lg[o] += xr * sB[r * 10 + o];
  }

  float m = lg[0];
  #pragma unroll
  for (int o = 1; o < OUTC; ++o) m = fmaxf(m, lg[o]);
  float s = 0.f;
  #pragma unroll
  for (int o = 0; o < OUTC; ++o) { lg[o] = __expf(lg[o] - m); s += lg[o]; }
  float invs = 1.0f / s;
  float* op = &out[(size_t)t * OUTC];
  #pragma unroll
  for (int o = 0; o < 5; ++o) {
    float2 p2; p2.x = lg[2 * o] * invs; p2.y = lg[2 * o + 1] * invs;
    *(float2*)&op[2 * o] = p2;
  }
}

extern "C" void kernel_launch(void* const* d_in, const int* in_sizes, int n_in,
                              void* d_out, int out_size, void* d_ws, size_t ws_size,
                              hipStream_t stream) {
  const float* x_c   = (const float*)d_in[0];
  const float* x_t   = (const float*)d_in[1];
  const float* x_p   = (const float*)d_in[2];
  const float* W_col = (const float*)d_in[3];
  const float* b_col = (const float*)d_in[4];
  const float* Wn    = (const float*)d_in[5];
  const float* Wr    = (const float*)d_in[6];
  const float* b_lin = (const float*)d_in[7];
  const float* W_out = (const float*)d_in[8];
  const float* b_out = (const float*)d_in[9];
  const int* e_m_src = (const int*)d_in[10];
  const int* e_m_dst = (const int*)d_in[11];
  const int* e_i_src = (const int*)d_in[12];
  const int* e_i_dst = (const int*)d_in[13];
  float* out = (float*)d_out;

  // ---- workspace carve-out (~27 MB; ws_size = 256 MiB) ----
  size_t cursor = 0;
  char* base = (char*)d_ws;
  auto alloc = [&](size_t bytes) {
    void* p = base + cursor;
    cursor += (bytes + 255) & ~(size_t)255;
    return p;
  };
  float* y_c  = (float*)alloc((size_t)NCV * YST * 4);              // 6.4 MB
  float* y_p  = (float*)alloc((size_t)NPV * YST * 4);              // 3.2 MB
  int nheads = NCV + NPV + 2 * NTV;
  int* heads  = (int*)alloc((size_t)nheads * 4);                   // 3.0 MB
  int* head_c  = heads;
  int* head_p  = heads + NCV;
  int* head_tm = heads + NCV + NPV;
  int* head_ti = heads + NCV + NPV + NTV;
  int2* nxt2_mc = (int2*)alloc((size_t)EMV * 8);                   // 2.4 MB
  int2* nxt2_mt = (int2*)alloc((size_t)EMV * 8);                   // 2.4 MB
  int2* nxt2_ip = (int2*)alloc((size_t)EIV * 8);                   // 4.8 MB
  int2* nxt2_it = (int2*)alloc((size_t)EIV * 8);                   // 4.8 MB
  float* B    = (float*)alloc(450 * 4);

  // ---- K0: fused per-column folding (blocks 0..9) + heads init (blocks 10..127) ----
  fold_heads<<<128, 256, 0, stream>>>(
      W_col, b_col, Wn, Wr, b_lin, W_out, b_out, heads, nheads, B);

  // ---- K1: customer/product-side lists ----
  build_cp<<<(EIV / 4 + 255) / 256, 256, 0, stream>>>(
      e_m_src, e_m_dst, e_i_src, e_i_dst,
      head_c, head_p, nxt2_mc, nxt2_ip);

  // ---- K2: t-side lists (overlapped) + gather/project y ----
  gather_y_buildt<<<(EIV / 4 + 255) / 256, 256, 0, stream>>>(
      x_t, e_m_src, e_m_dst, e_i_src, e_i_dst,
      head_c, head_p, nxt2_mc, nxt2_ip,
      head_tm, head_ti, nxt2_mt, nxt2_it,
      x_c, x_p, B, y_c, y_p);

  // ---- K3: gather y into transactions + combine + softmax ----
  gather_t<<<(NTV + 255) / 256, 256, 0, stream>>>(
      y_c, y_p, x_t, head_tm, head_ti, nxt2_mt, nxt2_it, B, out);
}